// Round 7
// baseline (290.285 us; speedup 1.0000x reference)
//
#include <hip/hip_runtime.h>
#include <hip/hip_fp16.h>

// ---------------------------------------------------------------------------
// EncodedGCN, round 6:
//  - x gather table -> fp16 (1.6MB, L2-resident; 16B/row)
//  - CSR weights pre-scaled by dinv[src] (k_prep) -> no dinv gather in passes
//  - pass1 4 lanes/node, butterfly-reduced; each lane writes 1/4 of t
//  - non-temporal loads on the streaming CSR in both passes
// Build pipeline (hist/scan/scatter/sort) unchanged.
// ---------------------------------------------------------------------------

#define NBLKA  256
#define BSH    7
#define BNODES 128
#define MAXBK  784

__global__ void k_senc(const float* __restrict__ sv, const float* __restrict__ w1,
                       const float* __restrict__ b1, const float* __restrict__ w2,
                       const float* __restrict__ b2, float* __restrict__ senc) {
    __shared__ float hid[32];
    int j = threadIdx.x;
    if (j < 32) {
        float acc = b1[j];
        #pragma unroll 8
        for (int k = 0; k < 64; ++k) acc += sv[k] * w1[k * 32 + j];
        hid[j] = acc > 0.f ? acc : 0.f;
    }
    __syncthreads();
    if (j == 0) {
        float acc = b2[0];
        #pragma unroll 8
        for (int k = 0; k < 32; ++k) acc += hid[k] * w2[k];
        senc[0] = acc;
    }
}

__global__ void k_hist(const int* __restrict__ ei, int* __restrict__ hist,
                       int E, int EPB, int NBK) {
    __shared__ int lh[MAXBK];
    for (int k = threadIdx.x; k < NBK; k += blockDim.x) lh[k] = 0;
    __syncthreads();
    int b = blockIdx.x;
    int e0 = b * EPB, e1 = min(E, e0 + EPB);
    for (int e = e0 + threadIdx.x; e < e1; e += blockDim.x)
        atomicAdd(&lh[ei[E + e] >> BSH], 1);
    __syncthreads();
    for (int k = threadIdx.x; k < NBK; k += blockDim.x)
        hist[(size_t)k * NBLKA + b] = lh[k];
}

__global__ void k_scan1(int* __restrict__ data, int* __restrict__ bsum, int nflat) {
    __shared__ int s[512];
    int i = blockIdx.x * 512 + threadIdx.x;
    int v = (i < nflat) ? data[i] : 0;
    s[threadIdx.x] = v;
    __syncthreads();
    for (int off = 1; off < 512; off <<= 1) {
        int tv = (threadIdx.x >= off) ? s[threadIdx.x - off] : 0;
        __syncthreads();
        if (threadIdx.x >= off) s[threadIdx.x] += tv;
        __syncthreads();
    }
    if (i < nflat) data[i] = s[threadIdx.x] - v;
    if (threadIdx.x == 511) bsum[blockIdx.x] = s[511];
}

__global__ void k_scan2(int* __restrict__ bsum, int nb) {
    __shared__ int s[512];
    int v = (threadIdx.x < nb) ? bsum[threadIdx.x] : 0;
    s[threadIdx.x] = v;
    __syncthreads();
    for (int off = 1; off < 512; off <<= 1) {
        int tv = (threadIdx.x >= off) ? s[threadIdx.x - off] : 0;
        __syncthreads();
        if (threadIdx.x >= off) s[threadIdx.x] += tv;
        __syncthreads();
    }
    if (threadIdx.x < nb) bsum[threadIdx.x] = s[threadIdx.x] - v;
}

__global__ void k_scan3(int* __restrict__ data, const int* __restrict__ bsum, int nflat) {
    int i = blockIdx.x * 512 + threadIdx.x;
    if (i < nflat) data[i] += bsum[i >> 9];
}

__global__ void k_scatter(const int* __restrict__ ei, const float* __restrict__ ew,
                          const int* __restrict__ scanned, int2* __restrict__ ebuf,
                          int E, int EPB, int NBK) {
    __shared__ int lbase[MAXBK];
    int b = blockIdx.x;
    for (int k = threadIdx.x; k < NBK; k += blockDim.x)
        lbase[k] = scanned[(size_t)k * NBLKA + b];
    __syncthreads();
    int e0 = b * EPB, e1 = min(E, e0 + EPB);
    for (int e = e0 + threadIdx.x; e < e1; e += blockDim.x) {
        int c = ei[E + e];
        int r = ei[e];
        int k = c >> BSH;
        int pos = atomicAdd(&lbase[k], 1);
        ebuf[pos] = make_int2(r | ((c & (BNODES - 1)) << 25), __float_as_int(ew[e]));
    }
}

__global__ void k_sort(const int* __restrict__ scanned, const int2* __restrict__ ebuf,
                       int* __restrict__ row, float* __restrict__ dinv,
                       int2* __restrict__ csr, int n, int E, int NBK) {
    __shared__ int lcnt[BNODES];
    __shared__ int lofs[BNODES];
    __shared__ float lw[BNODES];
    int k = blockIdx.x;
    if (threadIdx.x < BNODES) { lcnt[threadIdx.x] = 0; lw[threadIdx.x] = 1.0f; }
    __syncthreads();
    int bs = scanned[(size_t)k * NBLKA];
    int be = (k + 1 < NBK) ? scanned[(size_t)(k + 1) * NBLKA] : E;
    for (int s = bs + threadIdx.x; s < be; s += blockDim.x) {
        int2 ent = ebuf[s];
        int cl = ((unsigned)ent.x) >> 25;
        atomicAdd(&lcnt[cl], 1);
        atomicAdd(&lw[cl], __int_as_float(ent.y));
    }
    __syncthreads();
    int v = (threadIdx.x < BNODES) ? lcnt[threadIdx.x] : 0;
    if (threadIdx.x < BNODES) lofs[threadIdx.x] = v;
    __syncthreads();
    for (int off = 1; off < BNODES; off <<= 1) {
        int tv = 0;
        if (threadIdx.x < BNODES && threadIdx.x >= off) tv = lofs[threadIdx.x - off];
        __syncthreads();
        if (threadIdx.x < BNODES && threadIdx.x >= off) lofs[threadIdx.x] += tv;
        __syncthreads();
    }
    if (threadIdx.x < BNODES) {
        int excl = lofs[threadIdx.x] - v;
        lofs[threadIdx.x] = excl;
        int i = k * BNODES + threadIdx.x;
        if (i < n) {
            row[i] = bs + excl;
            dinv[i] = rsqrtf(lw[threadIdx.x]);
        }
    }
    if (k == NBK - 1 && threadIdx.x == 0) row[n] = E;
    __syncthreads();
    for (int s = bs + threadIdx.x; s < be; s += blockDim.x) {
        int2 ent = ebuf[s];
        int cl = ((unsigned)ent.x) >> 25;
        int pos = bs + atomicAdd(&lofs[cl], 1);
        csr[pos] = make_int2(ent.x & 0x01FFFFFF, ent.y);
    }
}

// pre-scale csr weight by dinv[src]; build fp16 x table
__global__ void k_prep(int2* __restrict__ csr, const float* __restrict__ dinv, int E) {
    int e = blockIdx.x * blockDim.x + threadIdx.x;
    if (e >= E) return;
    int2 ent = csr[e];
    csr[e].y = __float_as_int(__int_as_float(ent.y) * dinv[ent.x]);
}

__global__ void k_xh(const float* __restrict__ x, __half* __restrict__ xh, int n) {
    int i = blockIdx.x * blockDim.x + threadIdx.x;
    if (i >= n) return;
    const float4* xi = reinterpret_cast<const float4*>(x + (size_t)i * 8);
    float4 u = xi[0], v = xi[1];
    __half2 h0 = __floats2half2_rn(u.x, u.y);
    __half2 h1 = __floats2half2_rn(u.z, u.w);
    __half2 h2 = __floats2half2_rn(v.x, v.y);
    __half2 h3 = __floats2half2_rn(v.z, v.w);
    uint4 w;
    w.x = *reinterpret_cast<unsigned*>(&h0);
    w.y = *reinterpret_cast<unsigned*>(&h1);
    w.z = *reinterpret_cast<unsigned*>(&h2);
    w.w = *reinterpret_cast<unsigned*>(&h3);
    reinterpret_cast<uint4*>(xh + (size_t)i * 8)[0] = w;
}

__device__ inline int2 nt_load_int2(const int2* p) {
    unsigned long long v = __builtin_nontemporal_load(
        reinterpret_cast<const unsigned long long*>(p));
    int2 r;
    r.x = (int)(v & 0xFFFFFFFFull);
    r.y = (int)(v >> 32);
    return r;
}

// pass1, 4 lanes/node: agg9 gather (fp16 x) + conv1 + lrelu + conv2 -> t fp16
__global__ void k_pass1(const int* __restrict__ row, const int2* __restrict__ csr,
                        const float* __restrict__ dinv, const __half* __restrict__ xh,
                        const float* __restrict__ senc,
                        const float* __restrict__ W1, const float* __restrict__ b1,
                        const float* __restrict__ W2, __half* __restrict__ th, int n) {
    __shared__ float sW1[288];
    __shared__ float sb1[32];
    __shared__ float sW2[512];
    for (int j = threadIdx.x; j < 288; j += blockDim.x) sW1[j] = W1[j];
    for (int j = threadIdx.x; j < 512; j += blockDim.x) sW2[j] = W2[j];
    if (threadIdx.x < 32) sb1[threadIdx.x] = b1[threadIdx.x];
    __syncthreads();
    int g = blockIdx.x * blockDim.x + threadIdx.x;
    int i = g >> 2;
    int quad = g & 3;
    if (i >= n) return;
    float di = dinv[i];
    float a[8];
    float sw;  // sum of pre-scaled weights (+ di for self)
    if (quad == 0) {
        const uint4* xp = reinterpret_cast<const uint4*>(xh + (size_t)i * 8);
        uint4 w = xp[0];
        const __half2* hh = reinterpret_cast<const __half2*>(&w);
        #pragma unroll
        for (int q = 0; q < 4; ++q) {
            float2 f = __half22float2(hh[q]);
            a[2 * q] = di * f.x; a[2 * q + 1] = di * f.y;
        }
        sw = di;
    } else {
        #pragma unroll
        for (int q = 0; q < 8; ++q) a[q] = 0.f;
        sw = 0.f;
    }
    int s0 = row[i], s1 = row[i + 1];
    for (int s = s0 + quad; s < s1; s += 4) {
        int2 ent = nt_load_int2(csr + s);
        float wpre = __int_as_float(ent.y);
        const uint4* xp = reinterpret_cast<const uint4*>(xh + (size_t)ent.x * 8);
        uint4 w = xp[0];
        const __half2* hh = reinterpret_cast<const __half2*>(&w);
        #pragma unroll
        for (int q = 0; q < 4; ++q) {
            float2 f = __half22float2(hh[q]);
            a[2 * q] += wpre * f.x; a[2 * q + 1] += wpre * f.y;
        }
        sw += wpre;
    }
    // butterfly: all 4 lanes end with full sums
    #pragma unroll
    for (int q = 0; q < 8; ++q) a[q] += __shfl_xor(a[q], 1);
    sw += __shfl_xor(sw, 1);
    #pragma unroll
    for (int q = 0; q < 8; ++q) a[q] += __shfl_xor(a[q], 2);
    sw += __shfl_xor(sw, 2);
    // scale by di: a_true = di * a, senc coeff = di * sw
    float a8 = di * sw * senc[0];
    float h[32];
    #pragma unroll
    for (int j = 0; j < 32; ++j) {
        float acc = sb1[j] + a8 * sW1[8 * 32 + j];
        #pragma unroll
        for (int f = 0; f < 8; ++f) acc += (di * a[f]) * sW1[f * 32 + j];
        h[j] = acc > 0.f ? acc : 0.01f * acc;
    }
    // each lane computes its quarter of t and stores 8B
    unsigned u[2];
    #pragma unroll
    for (int p2 = 0; p2 < 2; ++p2) {
        int q0 = quad * 4 + 2 * p2;
        float t0 = 0.f, t1 = 0.f;
        #pragma unroll
        for (int j = 0; j < 32; ++j) {
            t0 += h[j] * sW2[j * 16 + q0];
            t1 += h[j] * sW2[j * 16 + q0 + 1];
        }
        __half2 hv = __floats2half2_rn(t0, t1);
        u[p2] = *reinterpret_cast<unsigned*>(&hv);
    }
    reinterpret_cast<uint2*>(th + (size_t)i * 16 + quad * 4)[0] = make_uint2(u[0], u[1]);
}

// pass2, 4 lanes/node: agg16 gather (fp16 t) + b2 + lrelu + fc -> out
__global__ void k_pass2(const int* __restrict__ row, const int2* __restrict__ csr,
                        const float* __restrict__ dinv, const __half* __restrict__ th,
                        const float* __restrict__ b2, const float* __restrict__ fw,
                        const float* __restrict__ fb, float* __restrict__ out, int n) {
    __shared__ float sb2[16];
    __shared__ float sfw[16];
    if (threadIdx.x < 16) { sb2[threadIdx.x] = b2[threadIdx.x]; sfw[threadIdx.x] = fw[threadIdx.x]; }
    __syncthreads();
    int g = blockIdx.x * blockDim.x + threadIdx.x;
    int i = g >> 2;
    int quad = g & 3;
    if (i >= n) return;
    float di = dinv[i];
    float acc[16];
    if (quad == 0) {
        const uint4* tp = reinterpret_cast<const uint4*>(th + (size_t)i * 16);
        uint4 w0 = tp[0], w1 = tp[1];
        const __half2* hh0 = reinterpret_cast<const __half2*>(&w0);
        const __half2* hh1 = reinterpret_cast<const __half2*>(&w1);
        #pragma unroll
        for (int q = 0; q < 4; ++q) {
            float2 f0 = __half22float2(hh0[q]);
            float2 f1 = __half22float2(hh1[q]);
            acc[2 * q + 0] = di * f0.x; acc[2 * q + 1] = di * f0.y;
            acc[8 + 2 * q + 0] = di * f1.x; acc[8 + 2 * q + 1] = di * f1.y;
        }
    } else {
        #pragma unroll
        for (int q = 0; q < 16; ++q) acc[q] = 0.f;
    }
    int s0 = row[i], s1 = row[i + 1];
    for (int s = s0 + quad; s < s1; s += 4) {
        int2 ent = nt_load_int2(csr + s);
        float wpre = __int_as_float(ent.y);
        const uint4* tp = reinterpret_cast<const uint4*>(th + (size_t)ent.x * 16);
        uint4 w0 = tp[0], w1 = tp[1];
        const __half2* hh0 = reinterpret_cast<const __half2*>(&w0);
        const __half2* hh1 = reinterpret_cast<const __half2*>(&w1);
        #pragma unroll
        for (int q = 0; q < 4; ++q) {
            float2 f0 = __half22float2(hh0[q]);
            float2 f1 = __half22float2(hh1[q]);
            acc[2 * q + 0] += wpre * f0.x; acc[2 * q + 1] += wpre * f0.y;
            acc[8 + 2 * q + 0] += wpre * f1.x; acc[8 + 2 * q + 1] += wpre * f1.y;
        }
    }
    #pragma unroll
    for (int q = 0; q < 16; ++q) acc[q] += __shfl_xor(acc[q], 1);
    #pragma unroll
    for (int q = 0; q < 16; ++q) acc[q] += __shfl_xor(acc[q], 2);
    if (quad) return;
    float o = fb[0];
    #pragma unroll
    for (int q = 0; q < 16; ++q) {
        float v = di * acc[q] + sb2[q];
        v = v > 0.f ? v : 0.01f * v;
        o += v * sfw[q];
    }
    out[i] = o;
}

extern "C" void kernel_launch(void* const* d_in, const int* in_sizes, int n_in,
                              void* d_out, int out_size, void* d_ws, size_t ws_size,
                              hipStream_t stream) {
    const float* x      = (const float*)d_in[0];
    const int*   ei     = (const int*)d_in[1];
    const float* ew     = (const float*)d_in[2];
    const float* sv     = (const float*)d_in[3];
    const float* sfc1w  = (const float*)d_in[4];
    const float* sfc1b  = (const float*)d_in[5];
    const float* sfc2w  = (const float*)d_in[6];
    const float* sfc2b  = (const float*)d_in[7];
    const float* conv1w = (const float*)d_in[8];
    const float* conv1b = (const float*)d_in[9];
    const float* conv2w = (const float*)d_in[10];
    const float* conv2b = (const float*)d_in[11];
    const float* fc1w   = (const float*)d_in[12];
    const float* fc1b   = (const float*)d_in[13];

    const int n = in_sizes[0] / 8;
    const int E = in_sizes[2];

    const int NBK   = (n + BNODES - 1) >> BSH;
    const int nflat = NBK * NBLKA;
    const int EPB   = (E + NBLKA - 1) / NBLKA;
    const int nb1   = (nflat + 511) / 512;

    size_t off = 0;
    auto alloc = [&](size_t words) { size_t o = off; off += (words + 3) & ~(size_t)3; return o; };
    float*  base = (float*)d_ws;
    float*  senc = base + alloc(4);
    float*  dinv = base + alloc(n);
    int*    rowp = (int*)(base + alloc(n + 1));
    int*    hist = (int*)(base + alloc(nflat));
    int*    bsum = (int*)(base + alloc(512));
    int2*   ebuf = (int2*)(base + alloc((size_t)2 * E));
    int2*   csr  = (int2*)(base + alloc((size_t)2 * E));
    __half* xh   = (__half*)(base + alloc((size_t)4 * n));  // n*8 halfs
    __half* th   = (__half*)(base + alloc((size_t)8 * n));  // n*16 halfs

    const int BT = 256;
    const int gN = (n + BT - 1) / BT;
    const int gE = (E + BT - 1) / BT;
    const int g4 = ((size_t)4 * n + BT - 1) / BT;

    k_senc<<<1, 64, 0, stream>>>(sv, sfc1w, sfc1b, sfc2w, sfc2b, senc);
    k_hist<<<NBLKA, 256, 0, stream>>>(ei, hist, E, EPB, NBK);
    k_scan1<<<nb1, 512, 0, stream>>>(hist, bsum, nflat);
    k_scan2<<<1, 512, 0, stream>>>(bsum, nb1);
    k_scan3<<<nb1, 512, 0, stream>>>(hist, bsum, nflat);
    k_scatter<<<NBLKA, 256, 0, stream>>>(ei, ew, hist, ebuf, E, EPB, NBK);
    k_sort<<<NBK, 256, 0, stream>>>(hist, ebuf, rowp, dinv, csr, n, E, NBK);
    k_prep<<<gE, BT, 0, stream>>>(csr, dinv, E);
    k_xh<<<gN, BT, 0, stream>>>(x, xh, n);
    k_pass1<<<g4, BT, 0, stream>>>(rowp, csr, dinv, xh, senc,
                                   conv1w, conv1b, conv2w, th, n);
    k_pass2<<<g4, BT, 0, stream>>>(rowp, csr, dinv, th,
                                   conv2b, fc1w, fc1b, (float*)d_out, n);
}

// Round 8
// 138.872 us; speedup vs baseline: 2.0903x; 2.0903x over previous
//
#include <hip/hip_runtime.h>
#include <hip/hip_fp16.h>

// ---------------------------------------------------------------------------
// EncodedGCN, round 7: round-5 structure (2-lane pass1 / 4-lane pass2, plain
// cached loads) + fp16 x gather table + CSR weights pre-scaled by dinv[src].
// Round-6 post-mortem: nt loads de-amortized the CSR stream's L2 lines and
// the 4-lane pass1 spilled h[32] to scratch (450MB phantom WRITE) -> reverted.
// ---------------------------------------------------------------------------

#define NBLKA  256
#define BSH    7
#define BNODES 128
#define MAXBK  784

__global__ void k_senc(const float* __restrict__ sv, const float* __restrict__ w1,
                       const float* __restrict__ b1, const float* __restrict__ w2,
                       const float* __restrict__ b2, float* __restrict__ senc) {
    __shared__ float hid[32];
    int j = threadIdx.x;
    if (j < 32) {
        float acc = b1[j];
        #pragma unroll 8
        for (int k = 0; k < 64; ++k) acc += sv[k] * w1[k * 32 + j];
        hid[j] = acc > 0.f ? acc : 0.f;
    }
    __syncthreads();
    if (j == 0) {
        float acc = b2[0];
        #pragma unroll 8
        for (int k = 0; k < 32; ++k) acc += hid[k] * w2[k];
        senc[0] = acc;
    }
}

__global__ void k_hist(const int* __restrict__ ei, int* __restrict__ hist,
                       int E, int EPB, int NBK) {
    __shared__ int lh[MAXBK];
    for (int k = threadIdx.x; k < NBK; k += blockDim.x) lh[k] = 0;
    __syncthreads();
    int b = blockIdx.x;
    int e0 = b * EPB, e1 = min(E, e0 + EPB);
    for (int e = e0 + threadIdx.x; e < e1; e += blockDim.x)
        atomicAdd(&lh[ei[E + e] >> BSH], 1);
    __syncthreads();
    for (int k = threadIdx.x; k < NBK; k += blockDim.x)
        hist[(size_t)k * NBLKA + b] = lh[k];
}

__global__ void k_scan1(int* __restrict__ data, int* __restrict__ bsum, int nflat) {
    __shared__ int s[512];
    int i = blockIdx.x * 512 + threadIdx.x;
    int v = (i < nflat) ? data[i] : 0;
    s[threadIdx.x] = v;
    __syncthreads();
    for (int off = 1; off < 512; off <<= 1) {
        int tv = (threadIdx.x >= off) ? s[threadIdx.x - off] : 0;
        __syncthreads();
        if (threadIdx.x >= off) s[threadIdx.x] += tv;
        __syncthreads();
    }
    if (i < nflat) data[i] = s[threadIdx.x] - v;
    if (threadIdx.x == 511) bsum[blockIdx.x] = s[511];
}

__global__ void k_scan2(int* __restrict__ bsum, int nb) {
    __shared__ int s[512];
    int v = (threadIdx.x < nb) ? bsum[threadIdx.x] : 0;
    s[threadIdx.x] = v;
    __syncthreads();
    for (int off = 1; off < 512; off <<= 1) {
        int tv = (threadIdx.x >= off) ? s[threadIdx.x - off] : 0;
        __syncthreads();
        if (threadIdx.x >= off) s[threadIdx.x] += tv;
        __syncthreads();
    }
    if (threadIdx.x < nb) bsum[threadIdx.x] = s[threadIdx.x] - v;
}

__global__ void k_scan3(int* __restrict__ data, const int* __restrict__ bsum, int nflat) {
    int i = blockIdx.x * 512 + threadIdx.x;
    if (i < nflat) data[i] += bsum[i >> 9];
}

__global__ void k_scatter(const int* __restrict__ ei, const float* __restrict__ ew,
                          const int* __restrict__ scanned, int2* __restrict__ ebuf,
                          int E, int EPB, int NBK) {
    __shared__ int lbase[MAXBK];
    int b = blockIdx.x;
    for (int k = threadIdx.x; k < NBK; k += blockDim.x)
        lbase[k] = scanned[(size_t)k * NBLKA + b];
    __syncthreads();
    int e0 = b * EPB, e1 = min(E, e0 + EPB);
    for (int e = e0 + threadIdx.x; e < e1; e += blockDim.x) {
        int c = ei[E + e];
        int r = ei[e];
        int k = c >> BSH;
        int pos = atomicAdd(&lbase[k], 1);
        ebuf[pos] = make_int2(r | ((c & (BNODES - 1)) << 25), __float_as_int(ew[e]));
    }
}

__global__ void k_sort(const int* __restrict__ scanned, const int2* __restrict__ ebuf,
                       int* __restrict__ row, float* __restrict__ dinv,
                       int2* __restrict__ csr, int n, int E, int NBK) {
    __shared__ int lcnt[BNODES];
    __shared__ int lofs[BNODES];
    __shared__ float lw[BNODES];
    int k = blockIdx.x;
    if (threadIdx.x < BNODES) { lcnt[threadIdx.x] = 0; lw[threadIdx.x] = 1.0f; }
    __syncthreads();
    int bs = scanned[(size_t)k * NBLKA];
    int be = (k + 1 < NBK) ? scanned[(size_t)(k + 1) * NBLKA] : E;
    for (int s = bs + threadIdx.x; s < be; s += blockDim.x) {
        int2 ent = ebuf[s];
        int cl = ((unsigned)ent.x) >> 25;
        atomicAdd(&lcnt[cl], 1);
        atomicAdd(&lw[cl], __int_as_float(ent.y));
    }
    __syncthreads();
    int v = (threadIdx.x < BNODES) ? lcnt[threadIdx.x] : 0;
    if (threadIdx.x < BNODES) lofs[threadIdx.x] = v;
    __syncthreads();
    for (int off = 1; off < BNODES; off <<= 1) {
        int tv = 0;
        if (threadIdx.x < BNODES && threadIdx.x >= off) tv = lofs[threadIdx.x - off];
        __syncthreads();
        if (threadIdx.x < BNODES && threadIdx.x >= off) lofs[threadIdx.x] += tv;
        __syncthreads();
    }
    if (threadIdx.x < BNODES) {
        int excl = lofs[threadIdx.x] - v;
        lofs[threadIdx.x] = excl;
        int i = k * BNODES + threadIdx.x;
        if (i < n) {
            row[i] = bs + excl;
            dinv[i] = rsqrtf(lw[threadIdx.x]);
        }
    }
    if (k == NBK - 1 && threadIdx.x == 0) row[n] = E;
    __syncthreads();
    for (int s = bs + threadIdx.x; s < be; s += blockDim.x) {
        int2 ent = ebuf[s];
        int cl = ((unsigned)ent.x) >> 25;
        int pos = bs + atomicAdd(&lofs[cl], 1);
        csr[pos] = make_int2(ent.x & 0x01FFFFFF, ent.y);
    }
}

// pre-scale csr weight by dinv[src]; full 8B rewrite (no partial-struct store)
__global__ void k_prep(int2* __restrict__ csr, const float* __restrict__ dinv, int E) {
    int e = blockIdx.x * blockDim.x + threadIdx.x;
    if (e >= E) return;
    int2 ent = csr[e];
    ent.y = __float_as_int(__int_as_float(ent.y) * dinv[ent.x]);
    csr[e] = ent;
}

// fp16 x table (16B/row, 1.6MB)
__global__ void k_xh(const float* __restrict__ x, __half* __restrict__ xh, int n) {
    int i = blockIdx.x * blockDim.x + threadIdx.x;
    if (i >= n) return;
    const float4* xi = reinterpret_cast<const float4*>(x + (size_t)i * 8);
    float4 u = xi[0], v = xi[1];
    __half2 h0 = __floats2half2_rn(u.x, u.y);
    __half2 h1 = __floats2half2_rn(u.z, u.w);
    __half2 h2 = __floats2half2_rn(v.x, v.y);
    __half2 h3 = __floats2half2_rn(v.z, v.w);
    uint4 w;
    w.x = *reinterpret_cast<unsigned*>(&h0);
    w.y = *reinterpret_cast<unsigned*>(&h1);
    w.z = *reinterpret_cast<unsigned*>(&h2);
    w.w = *reinterpret_cast<unsigned*>(&h3);
    reinterpret_cast<uint4*>(xh + (size_t)i * 8)[0] = w;
}

// pass1, 2 lanes/node: agg9 gather (fp16 xh, prescaled w) + conv1 + lrelu
// + conv2 -> t fp16. Only half==0 runs the dense tail (round-5 structure).
__global__ void k_pass1(const int* __restrict__ row, const int2* __restrict__ csr,
                        const float* __restrict__ dinv, const __half* __restrict__ xh,
                        const float* __restrict__ senc,
                        const float* __restrict__ W1, const float* __restrict__ b1,
                        const float* __restrict__ W2, __half* __restrict__ th, int n) {
    __shared__ float sW1[288];
    __shared__ float sb1[32];
    __shared__ float sW2[512];
    for (int j = threadIdx.x; j < 288; j += blockDim.x) sW1[j] = W1[j];
    for (int j = threadIdx.x; j < 512; j += blockDim.x) sW2[j] = W2[j];
    if (threadIdx.x < 32) sb1[threadIdx.x] = b1[threadIdx.x];
    __syncthreads();
    int g = blockIdx.x * blockDim.x + threadIdx.x;
    int i = g >> 1;
    int half = g & 1;
    if (i >= n) return;
    float di = dinv[i];
    float a[8];
    float sw;
    if (half == 0) {
        const uint4* xp = reinterpret_cast<const uint4*>(xh + (size_t)i * 8);
        uint4 w = xp[0];
        const __half2* hh = reinterpret_cast<const __half2*>(&w);
        #pragma unroll
        for (int q = 0; q < 4; ++q) {
            float2 f = __half22float2(hh[q]);
            a[2 * q] = di * f.x; a[2 * q + 1] = di * f.y;
        }
        sw = di;
    } else {
        #pragma unroll
        for (int q = 0; q < 8; ++q) a[q] = 0.f;
        sw = 0.f;
    }
    int s0 = row[i], s1 = row[i + 1];
    for (int s = s0 + half; s < s1; s += 2) {
        int2 ent = csr[s];
        float wpre = __int_as_float(ent.y);
        const uint4* xp = reinterpret_cast<const uint4*>(xh + (size_t)ent.x * 8);
        uint4 w = xp[0];
        const __half2* hh = reinterpret_cast<const __half2*>(&w);
        #pragma unroll
        for (int q = 0; q < 4; ++q) {
            float2 f = __half22float2(hh[q]);
            a[2 * q] += wpre * f.x; a[2 * q + 1] += wpre * f.y;
        }
        sw += wpre;
    }
    #pragma unroll
    for (int q = 0; q < 8; ++q) a[q] += __shfl_xor(a[q], 1);
    sw += __shfl_xor(sw, 1);
    if (half) return;
    // true agg = di * (partial); senc coeff = di * sw
    float a8 = di * sw * senc[0];
    float af[8];
    #pragma unroll
    for (int q = 0; q < 8; ++q) af[q] = di * a[q];
    float h[32];
    #pragma unroll
    for (int j = 0; j < 32; ++j) {
        float acc = sb1[j] + a8 * sW1[8 * 32 + j];
        #pragma unroll
        for (int f = 0; f < 8; ++f) acc += af[f] * sW1[f * 32 + j];
        h[j] = acc > 0.f ? acc : 0.01f * acc;
    }
    unsigned u[8];
    #pragma unroll
    for (int p2 = 0; p2 < 8; ++p2) {
        float t0 = 0.f, t1 = 0.f;
        #pragma unroll
        for (int j = 0; j < 32; ++j) {
            t0 += h[j] * sW2[j * 16 + 2 * p2];
            t1 += h[j] * sW2[j * 16 + 2 * p2 + 1];
        }
        __half2 hv = __floats2half2_rn(t0, t1);
        u[p2] = *reinterpret_cast<unsigned*>(&hv);
    }
    uint4* tp = reinterpret_cast<uint4*>(th + (size_t)i * 16);
    tp[0] = make_uint4(u[0], u[1], u[2], u[3]);
    tp[1] = make_uint4(u[4], u[5], u[6], u[7]);
}

// pass2, 4 lanes/node: agg16 gather (fp16 t, prescaled w) + b2 + lrelu + fc
__global__ void k_pass2(const int* __restrict__ row, const int2* __restrict__ csr,
                        const float* __restrict__ dinv, const __half* __restrict__ th,
                        const float* __restrict__ b2, const float* __restrict__ fw,
                        const float* __restrict__ fb, float* __restrict__ out, int n) {
    __shared__ float sb2[16];
    __shared__ float sfw[16];
    if (threadIdx.x < 16) { sb2[threadIdx.x] = b2[threadIdx.x]; sfw[threadIdx.x] = fw[threadIdx.x]; }
    __syncthreads();
    int g = blockIdx.x * blockDim.x + threadIdx.x;
    int i = g >> 2;
    int quad = g & 3;
    if (i >= n) return;
    float di = dinv[i];
    float acc[16];
    if (quad == 0) {
        const uint4* tp = reinterpret_cast<const uint4*>(th + (size_t)i * 16);
        uint4 w0 = tp[0], w1 = tp[1];
        const __half2* hh0 = reinterpret_cast<const __half2*>(&w0);
        const __half2* hh1 = reinterpret_cast<const __half2*>(&w1);
        #pragma unroll
        for (int q = 0; q < 4; ++q) {
            float2 f0 = __half22float2(hh0[q]);
            float2 f1 = __half22float2(hh1[q]);
            acc[2 * q + 0] = di * f0.x; acc[2 * q + 1] = di * f0.y;
            acc[8 + 2 * q + 0] = di * f1.x; acc[8 + 2 * q + 1] = di * f1.y;
        }
    } else {
        #pragma unroll
        for (int q = 0; q < 16; ++q) acc[q] = 0.f;
    }
    int s0 = row[i], s1 = row[i + 1];
    for (int s = s0 + quad; s < s1; s += 4) {
        int2 ent = csr[s];
        float wpre = __int_as_float(ent.y);
        const uint4* tp = reinterpret_cast<const uint4*>(th + (size_t)ent.x * 16);
        uint4 w0 = tp[0], w1 = tp[1];
        const __half2* hh0 = reinterpret_cast<const __half2*>(&w0);
        const __half2* hh1 = reinterpret_cast<const __half2*>(&w1);
        #pragma unroll
        for (int q = 0; q < 4; ++q) {
            float2 f0 = __half22float2(hh0[q]);
            float2 f1 = __half22float2(hh1[q]);
            acc[2 * q + 0] += wpre * f0.x; acc[2 * q + 1] += wpre * f0.y;
            acc[8 + 2 * q + 0] += wpre * f1.x; acc[8 + 2 * q + 1] += wpre * f1.y;
        }
    }
    #pragma unroll
    for (int q = 0; q < 16; ++q) acc[q] += __shfl_xor(acc[q], 1);
    #pragma unroll
    for (int q = 0; q < 16; ++q) acc[q] += __shfl_xor(acc[q], 2);
    if (quad) return;
    float o = fb[0];
    #pragma unroll
    for (int q = 0; q < 16; ++q) {
        float v = di * acc[q] + sb2[q];
        v = v > 0.f ? v : 0.01f * v;
        o += v * sfw[q];
    }
    out[i] = o;
}

extern "C" void kernel_launch(void* const* d_in, const int* in_sizes, int n_in,
                              void* d_out, int out_size, void* d_ws, size_t ws_size,
                              hipStream_t stream) {
    const float* x      = (const float*)d_in[0];
    const int*   ei     = (const int*)d_in[1];
    const float* ew     = (const float*)d_in[2];
    const float* sv     = (const float*)d_in[3];
    const float* sfc1w  = (const float*)d_in[4];
    const float* sfc1b  = (const float*)d_in[5];
    const float* sfc2w  = (const float*)d_in[6];
    const float* sfc2b  = (const float*)d_in[7];
    const float* conv1w = (const float*)d_in[8];
    const float* conv1b = (const float*)d_in[9];
    const float* conv2w = (const float*)d_in[10];
    const float* conv2b = (const float*)d_in[11];
    const float* fc1w   = (const float*)d_in[12];
    const float* fc1b   = (const float*)d_in[13];

    const int n = in_sizes[0] / 8;
    const int E = in_sizes[2];

    const int NBK   = (n + BNODES - 1) >> BSH;
    const int nflat = NBK * NBLKA;
    const int EPB   = (E + NBLKA - 1) / NBLKA;
    const int nb1   = (nflat + 511) / 512;

    size_t off = 0;
    auto alloc = [&](size_t words) { size_t o = off; off += (words + 3) & ~(size_t)3; return o; };
    float*  base = (float*)d_ws;
    float*  senc = base + alloc(4);
    float*  dinv = base + alloc(n);
    int*    rowp = (int*)(base + alloc(n + 1));
    int*    hist = (int*)(base + alloc(nflat));
    int*    bsum = (int*)(base + alloc(512));
    int2*   ebuf = (int2*)(base + alloc((size_t)2 * E));
    int2*   csr  = (int2*)(base + alloc((size_t)2 * E));
    __half* xh   = (__half*)(base + alloc((size_t)4 * n));  // n*8 halfs
    __half* th   = (__half*)(base + alloc((size_t)8 * n));  // n*16 halfs

    const int BT = 256;
    const int gN = (n + BT - 1) / BT;
    const int gE = (E + BT - 1) / BT;
    const int g2 = ((size_t)2 * n + BT - 1) / BT;
    const int g4 = ((size_t)4 * n + BT - 1) / BT;

    k_senc<<<1, 64, 0, stream>>>(sv, sfc1w, sfc1b, sfc2w, sfc2b, senc);
    k_xh<<<gN, BT, 0, stream>>>(x, xh, n);
    k_hist<<<NBLKA, 256, 0, stream>>>(ei, hist, E, EPB, NBK);
    k_scan1<<<nb1, 512, 0, stream>>>(hist, bsum, nflat);
    k_scan2<<<1, 512, 0, stream>>>(bsum, nb1);
    k_scan3<<<nb1, 512, 0, stream>>>(hist, bsum, nflat);
    k_scatter<<<NBLKA, 256, 0, stream>>>(ei, ew, hist, ebuf, E, EPB, NBK);
    k_sort<<<NBK, 256, 0, stream>>>(hist, ebuf, rowp, dinv, csr, n, E, NBK);
    k_prep<<<gE, BT, 0, stream>>>(csr, dinv, E);
    k_pass1<<<g2, BT, 0, stream>>>(rowp, csr, dinv, xh, senc,
                                   conv1w, conv1b, conv2w, th, n);
    k_pass2<<<g4, BT, 0, stream>>>(rowp, csr, dinv, th,
                                   conv2b, fc1w, fc1b, (float*)d_out, n);
}

// Round 9
// 125.826 us; speedup vs baseline: 2.3070x; 1.1037x over previous
//
#include <hip/hip_runtime.h>
#include <hip/hip_fp16.h>

// ---------------------------------------------------------------------------
// EncodedGCN, round 8: register-lean 4-lane pass1.
// Each quad-lane gathers 1/4 of the edges; butterfly-> full a[8],sw; each lane
// computes 8 of 32 h's + 16 t-partials over its j-range; butterfly -> full t;
// lane stores its 8B quarter of th. W2 in LDS at stride 17 (bank-spread).
// Rest identical to round 7.
// ---------------------------------------------------------------------------

#define NBLKA  256
#define BSH    7
#define BNODES 128
#define MAXBK  784

__global__ void k_senc(const float* __restrict__ sv, const float* __restrict__ w1,
                       const float* __restrict__ b1, const float* __restrict__ w2,
                       const float* __restrict__ b2, float* __restrict__ senc) {
    __shared__ float hid[32];
    int j = threadIdx.x;
    if (j < 32) {
        float acc = b1[j];
        #pragma unroll 8
        for (int k = 0; k < 64; ++k) acc += sv[k] * w1[k * 32 + j];
        hid[j] = acc > 0.f ? acc : 0.f;
    }
    __syncthreads();
    if (j == 0) {
        float acc = b2[0];
        #pragma unroll 8
        for (int k = 0; k < 32; ++k) acc += hid[k] * w2[k];
        senc[0] = acc;
    }
}

__global__ void k_hist(const int* __restrict__ ei, int* __restrict__ hist,
                       int E, int EPB, int NBK) {
    __shared__ int lh[MAXBK];
    for (int k = threadIdx.x; k < NBK; k += blockDim.x) lh[k] = 0;
    __syncthreads();
    int b = blockIdx.x;
    int e0 = b * EPB, e1 = min(E, e0 + EPB);
    for (int e = e0 + threadIdx.x; e < e1; e += blockDim.x)
        atomicAdd(&lh[ei[E + e] >> BSH], 1);
    __syncthreads();
    for (int k = threadIdx.x; k < NBK; k += blockDim.x)
        hist[(size_t)k * NBLKA + b] = lh[k];
}

__global__ void k_scan1(int* __restrict__ data, int* __restrict__ bsum, int nflat) {
    __shared__ int s[512];
    int i = blockIdx.x * 512 + threadIdx.x;
    int v = (i < nflat) ? data[i] : 0;
    s[threadIdx.x] = v;
    __syncthreads();
    for (int off = 1; off < 512; off <<= 1) {
        int tv = (threadIdx.x >= off) ? s[threadIdx.x - off] : 0;
        __syncthreads();
        if (threadIdx.x >= off) s[threadIdx.x] += tv;
        __syncthreads();
    }
    if (i < nflat) data[i] = s[threadIdx.x] - v;
    if (threadIdx.x == 511) bsum[blockIdx.x] = s[511];
}

__global__ void k_scan2(int* __restrict__ bsum, int nb) {
    __shared__ int s[512];
    int v = (threadIdx.x < nb) ? bsum[threadIdx.x] : 0;
    s[threadIdx.x] = v;
    __syncthreads();
    for (int off = 1; off < 512; off <<= 1) {
        int tv = (threadIdx.x >= off) ? s[threadIdx.x - off] : 0;
        __syncthreads();
        if (threadIdx.x >= off) s[threadIdx.x] += tv;
        __syncthreads();
    }
    if (threadIdx.x < nb) bsum[threadIdx.x] = s[threadIdx.x] - v;
}

__global__ void k_scan3(int* __restrict__ data, const int* __restrict__ bsum, int nflat) {
    int i = blockIdx.x * 512 + threadIdx.x;
    if (i < nflat) data[i] += bsum[i >> 9];
}

__global__ void k_scatter(const int* __restrict__ ei, const float* __restrict__ ew,
                          const int* __restrict__ scanned, int2* __restrict__ ebuf,
                          int E, int EPB, int NBK) {
    __shared__ int lbase[MAXBK];
    int b = blockIdx.x;
    for (int k = threadIdx.x; k < NBK; k += blockDim.x)
        lbase[k] = scanned[(size_t)k * NBLKA + b];
    __syncthreads();
    int e0 = b * EPB, e1 = min(E, e0 + EPB);
    for (int e = e0 + threadIdx.x; e < e1; e += blockDim.x) {
        int c = ei[E + e];
        int r = ei[e];
        int k = c >> BSH;
        int pos = atomicAdd(&lbase[k], 1);
        ebuf[pos] = make_int2(r | ((c & (BNODES - 1)) << 25), __float_as_int(ew[e]));
    }
}

__global__ void k_sort(const int* __restrict__ scanned, const int2* __restrict__ ebuf,
                       int* __restrict__ row, float* __restrict__ dinv,
                       int2* __restrict__ csr, int n, int E, int NBK) {
    __shared__ int lcnt[BNODES];
    __shared__ int lofs[BNODES];
    __shared__ float lw[BNODES];
    int k = blockIdx.x;
    if (threadIdx.x < BNODES) { lcnt[threadIdx.x] = 0; lw[threadIdx.x] = 1.0f; }
    __syncthreads();
    int bs = scanned[(size_t)k * NBLKA];
    int be = (k + 1 < NBK) ? scanned[(size_t)(k + 1) * NBLKA] : E;
    for (int s = bs + threadIdx.x; s < be; s += blockDim.x) {
        int2 ent = ebuf[s];
        int cl = ((unsigned)ent.x) >> 25;
        atomicAdd(&lcnt[cl], 1);
        atomicAdd(&lw[cl], __int_as_float(ent.y));
    }
    __syncthreads();
    int v = (threadIdx.x < BNODES) ? lcnt[threadIdx.x] : 0;
    if (threadIdx.x < BNODES) lofs[threadIdx.x] = v;
    __syncthreads();
    for (int off = 1; off < BNODES; off <<= 1) {
        int tv = 0;
        if (threadIdx.x < BNODES && threadIdx.x >= off) tv = lofs[threadIdx.x - off];
        __syncthreads();
        if (threadIdx.x < BNODES && threadIdx.x >= off) lofs[threadIdx.x] += tv;
        __syncthreads();
    }
    if (threadIdx.x < BNODES) {
        int excl = lofs[threadIdx.x] - v;
        lofs[threadIdx.x] = excl;
        int i = k * BNODES + threadIdx.x;
        if (i < n) {
            row[i] = bs + excl;
            dinv[i] = rsqrtf(lw[threadIdx.x]);
        }
    }
    if (k == NBK - 1 && threadIdx.x == 0) row[n] = E;
    __syncthreads();
    for (int s = bs + threadIdx.x; s < be; s += blockDim.x) {
        int2 ent = ebuf[s];
        int cl = ((unsigned)ent.x) >> 25;
        int pos = bs + atomicAdd(&lofs[cl], 1);
        csr[pos] = make_int2(ent.x & 0x01FFFFFF, ent.y);
    }
}

__global__ void k_prep(int2* __restrict__ csr, const float* __restrict__ dinv, int E) {
    int e = blockIdx.x * blockDim.x + threadIdx.x;
    if (e >= E) return;
    int2 ent = csr[e];
    ent.y = __float_as_int(__int_as_float(ent.y) * dinv[ent.x]);
    csr[e] = ent;
}

__global__ void k_xh(const float* __restrict__ x, __half* __restrict__ xh, int n) {
    int i = blockIdx.x * blockDim.x + threadIdx.x;
    if (i >= n) return;
    const float4* xi = reinterpret_cast<const float4*>(x + (size_t)i * 8);
    float4 u = xi[0], v = xi[1];
    __half2 h0 = __floats2half2_rn(u.x, u.y);
    __half2 h1 = __floats2half2_rn(u.z, u.w);
    __half2 h2 = __floats2half2_rn(v.x, v.y);
    __half2 h3 = __floats2half2_rn(v.z, v.w);
    uint4 w;
    w.x = *reinterpret_cast<unsigned*>(&h0);
    w.y = *reinterpret_cast<unsigned*>(&h1);
    w.z = *reinterpret_cast<unsigned*>(&h2);
    w.w = *reinterpret_cast<unsigned*>(&h3);
    reinterpret_cast<uint4*>(xh + (size_t)i * 8)[0] = w;
}

// pass1, 4 lanes/node, register-lean distributed tail.
__global__ void k_pass1(const int* __restrict__ row, const int2* __restrict__ csr,
                        const float* __restrict__ dinv, const __half* __restrict__ xh,
                        const float* __restrict__ senc,
                        const float* __restrict__ W1, const float* __restrict__ b1,
                        const float* __restrict__ W2, __half* __restrict__ th, int n) {
    __shared__ float sW1[288];
    __shared__ float sb1[32];
    __shared__ float sW2[32 * 17];   // stride 17: quad j-ranges hit distinct banks
    for (int j = threadIdx.x; j < 288; j += blockDim.x) sW1[j] = W1[j];
    for (int j = threadIdx.x; j < 512; j += blockDim.x) sW2[(j >> 4) * 17 + (j & 15)] = W2[j];
    if (threadIdx.x < 32) sb1[threadIdx.x] = b1[threadIdx.x];
    __syncthreads();
    int g = blockIdx.x * blockDim.x + threadIdx.x;
    int i = g >> 2;
    int quad = g & 3;
    if (i >= n) return;
    float di = dinv[i];
    float a[8];
    float sw;
    if (quad == 0) {
        const uint4* xp = reinterpret_cast<const uint4*>(xh + (size_t)i * 8);
        uint4 w = xp[0];
        const __half2* hh = reinterpret_cast<const __half2*>(&w);
        #pragma unroll
        for (int q = 0; q < 4; ++q) {
            float2 f = __half22float2(hh[q]);
            a[2 * q] = di * f.x; a[2 * q + 1] = di * f.y;
        }
        sw = di;
    } else {
        #pragma unroll
        for (int q = 0; q < 8; ++q) a[q] = 0.f;
        sw = 0.f;
    }
    int s0 = row[i], s1 = row[i + 1];
    for (int s = s0 + quad; s < s1; s += 4) {
        int2 ent = csr[s];
        float wpre = __int_as_float(ent.y);
        const uint4* xp = reinterpret_cast<const uint4*>(xh + (size_t)ent.x * 8);
        uint4 w = xp[0];
        const __half2* hh = reinterpret_cast<const __half2*>(&w);
        #pragma unroll
        for (int q = 0; q < 4; ++q) {
            float2 f = __half22float2(hh[q]);
            a[2 * q] += wpre * f.x; a[2 * q + 1] += wpre * f.y;
        }
        sw += wpre;
    }
    // butterfly -> all 4 lanes hold full a, sw
    #pragma unroll
    for (int q = 0; q < 8; ++q) a[q] += __shfl_xor(a[q], 1);
    sw += __shfl_xor(sw, 1);
    #pragma unroll
    for (int q = 0; q < 8; ++q) a[q] += __shfl_xor(a[q], 2);
    sw += __shfl_xor(sw, 2);
    float a8 = di * sw * senc[0];
    float af[8];
    #pragma unroll
    for (int q = 0; q < 8; ++q) af[q] = di * a[q];
    // each lane: 8 h's (j = quad*8 + jj)
    float h[8];
    #pragma unroll
    for (int jj = 0; jj < 8; ++jj) {
        int j = quad * 8 + jj;
        float acc = sb1[j] + a8 * sW1[8 * 32 + j];
        #pragma unroll
        for (int f = 0; f < 8; ++f) acc += af[f] * sW1[f * 32 + j];
        h[jj] = acc > 0.f ? acc : 0.01f * acc;
    }
    // 16 t-partials over this lane's j-range
    float p[16];
    #pragma unroll
    for (int o = 0; o < 16; ++o) p[o] = 0.f;
    #pragma unroll
    for (int jj = 0; jj < 8; ++jj) {
        int j = quad * 8 + jj;
        #pragma unroll
        for (int o = 0; o < 16; ++o) p[o] += h[jj] * sW2[j * 17 + o];
    }
    // butterfly -> all lanes hold full t[16]
    #pragma unroll
    for (int o = 0; o < 16; ++o) p[o] += __shfl_xor(p[o], 1);
    #pragma unroll
    for (int o = 0; o < 16; ++o) p[o] += __shfl_xor(p[o], 2);
    // lane stores its quarter (8B)
    int o0 = quad * 4;
    __half2 hv0 = __floats2half2_rn(p[o0 + 0], p[o0 + 1]);
    __half2 hv1 = __floats2half2_rn(p[o0 + 2], p[o0 + 3]);
    uint2 st;
    st.x = *reinterpret_cast<unsigned*>(&hv0);
    st.y = *reinterpret_cast<unsigned*>(&hv1);
    reinterpret_cast<uint2*>(th + (size_t)i * 16 + o0)[0] = st;
}

// pass2, 4 lanes/node (unchanged from round 7)
__global__ void k_pass2(const int* __restrict__ row, const int2* __restrict__ csr,
                        const float* __restrict__ dinv, const __half* __restrict__ th,
                        const float* __restrict__ b2, const float* __restrict__ fw,
                        const float* __restrict__ fb, float* __restrict__ out, int n) {
    __shared__ float sb2[16];
    __shared__ float sfw[16];
    if (threadIdx.x < 16) { sb2[threadIdx.x] = b2[threadIdx.x]; sfw[threadIdx.x] = fw[threadIdx.x]; }
    __syncthreads();
    int g = blockIdx.x * blockDim.x + threadIdx.x;
    int i = g >> 2;
    int quad = g & 3;
    if (i >= n) return;
    float di = dinv[i];
    float acc[16];
    if (quad == 0) {
        const uint4* tp = reinterpret_cast<const uint4*>(th + (size_t)i * 16);
        uint4 w0 = tp[0], w1 = tp[1];
        const __half2* hh0 = reinterpret_cast<const __half2*>(&w0);
        const __half2* hh1 = reinterpret_cast<const __half2*>(&w1);
        #pragma unroll
        for (int q = 0; q < 4; ++q) {
            float2 f0 = __half22float2(hh0[q]);
            float2 f1 = __half22float2(hh1[q]);
            acc[2 * q + 0] = di * f0.x; acc[2 * q + 1] = di * f0.y;
            acc[8 + 2 * q + 0] = di * f1.x; acc[8 + 2 * q + 1] = di * f1.y;
        }
    } else {
        #pragma unroll
        for (int q = 0; q < 16; ++q) acc[q] = 0.f;
    }
    int s0 = row[i], s1 = row[i + 1];
    for (int s = s0 + quad; s < s1; s += 4) {
        int2 ent = csr[s];
        float wpre = __int_as_float(ent.y);
        const uint4* tp = reinterpret_cast<const uint4*>(th + (size_t)ent.x * 16);
        uint4 w0 = tp[0], w1 = tp[1];
        const __half2* hh0 = reinterpret_cast<const __half2*>(&w0);
        const __half2* hh1 = reinterpret_cast<const __half2*>(&w1);
        #pragma unroll
        for (int q = 0; q < 4; ++q) {
            float2 f0 = __half22float2(hh0[q]);
            float2 f1 = __half22float2(hh1[q]);
            acc[2 * q + 0] += wpre * f0.x; acc[2 * q + 1] += wpre * f0.y;
            acc[8 + 2 * q + 0] += wpre * f1.x; acc[8 + 2 * q + 1] += wpre * f1.y;
        }
    }
    #pragma unroll
    for (int q = 0; q < 16; ++q) acc[q] += __shfl_xor(acc[q], 1);
    #pragma unroll
    for (int q = 0; q < 16; ++q) acc[q] += __shfl_xor(acc[q], 2);
    if (quad) return;
    float o = fb[0];
    #pragma unroll
    for (int q = 0; q < 16; ++q) {
        float v = di * acc[q] + sb2[q];
        v = v > 0.f ? v : 0.01f * v;
        o += v * sfw[q];
    }
    out[i] = o;
}

extern "C" void kernel_launch(void* const* d_in, const int* in_sizes, int n_in,
                              void* d_out, int out_size, void* d_ws, size_t ws_size,
                              hipStream_t stream) {
    const float* x      = (const float*)d_in[0];
    const int*   ei     = (const int*)d_in[1];
    const float* ew     = (const float*)d_in[2];
    const float* sv     = (const float*)d_in[3];
    const float* sfc1w  = (const float*)d_in[4];
    const float* sfc1b  = (const float*)d_in[5];
    const float* sfc2w  = (const float*)d_in[6];
    const float* sfc2b  = (const float*)d_in[7];
    const float* conv1w = (const float*)d_in[8];
    const float* conv1b = (const float*)d_in[9];
    const float* conv2w = (const float*)d_in[10];
    const float* conv2b = (const float*)d_in[11];
    const float* fc1w   = (const float*)d_in[12];
    const float* fc1b   = (const float*)d_in[13];

    const int n = in_sizes[0] / 8;
    const int E = in_sizes[2];

    const int NBK   = (n + BNODES - 1) >> BSH;
    const int nflat = NBK * NBLKA;
    const int EPB   = (E + NBLKA - 1) / NBLKA;
    const int nb1   = (nflat + 511) / 512;

    size_t off = 0;
    auto alloc = [&](size_t words) { size_t o = off; off += (words + 3) & ~(size_t)3; return o; };
    float*  base = (float*)d_ws;
    float*  senc = base + alloc(4);
    float*  dinv = base + alloc(n);
    int*    rowp = (int*)(base + alloc(n + 1));
    int*    hist = (int*)(base + alloc(nflat));
    int*    bsum = (int*)(base + alloc(512));
    int2*   ebuf = (int2*)(base + alloc((size_t)2 * E));
    int2*   csr  = (int2*)(base + alloc((size_t)2 * E));
    __half* xh   = (__half*)(base + alloc((size_t)4 * n));
    __half* th   = (__half*)(base + alloc((size_t)8 * n));

    const int BT = 256;
    const int gN = (n + BT - 1) / BT;
    const int gE = (E + BT - 1) / BT;
    const int g4 = ((size_t)4 * n + BT - 1) / BT;

    k_senc<<<1, 64, 0, stream>>>(sv, sfc1w, sfc1b, sfc2w, sfc2b, senc);
    k_xh<<<gN, BT, 0, stream>>>(x, xh, n);
    k_hist<<<NBLKA, 256, 0, stream>>>(ei, hist, E, EPB, NBK);
    k_scan1<<<nb1, 512, 0, stream>>>(hist, bsum, nflat);
    k_scan2<<<1, 512, 0, stream>>>(bsum, nb1);
    k_scan3<<<nb1, 512, 0, stream>>>(hist, bsum, nflat);
    k_scatter<<<NBLKA, 256, 0, stream>>>(ei, ew, hist, ebuf, E, EPB, NBK);
    k_sort<<<NBK, 256, 0, stream>>>(hist, ebuf, rowp, dinv, csr, n, E, NBK);
    k_prep<<<gE, BT, 0, stream>>>(csr, dinv, E);
    k_pass1<<<g4, BT, 0, stream>>>(rowp, csr, dinv, xh, senc,
                                   conv1w, conv1b, conv2w, th, n);
    k_pass2<<<g4, BT, 0, stream>>>(rowp, csr, dinv, th,
                                   conv2b, fc1w, fc1b, (float*)d_out, n);
}